// Round 1
// baseline (1280.377 us; speedup 1.0000x reference)
//
#include <hip/hip_runtime.h>

#define BB 2
#define SS 2048
#define DIMM 1024
#define HH 16
#define DD 64
#define BHN (BB*HH)          // 32
#define MMN (BB*SS)          // 4096
#define ZSTRIDE ((size_t)MMN*DIMM)  // 4194304 elements per q/k/v region

typedef _Float16 f16;
typedef _Float16 f16x8 __attribute__((ext_vector_type(8)));
typedef float f32x4 __attribute__((ext_vector_type(4)));

static __device__ __forceinline__ f32x4 mfma16(f16x8 a, f16x8 b, f32x4 c) {
    return __builtin_amdgcn_mfma_f32_16x16x32_f16(a, b, c, 0, 0, 0);
}

// ---------------------------------------------------------------------------
// Kernel 1: cast+transpose the four weight matrices: W[k][n] fp32 -> Wt[n][k] f16
// grid (16,16,4), block 256
__global__ __launch_bounds__(256) void k_wt(const float* wq, const float* wk,
                                            const float* wv, const float* wo,
                                            f16* wt) {
    __shared__ float T[64][65];
    const float* W = blockIdx.z == 0 ? wq : blockIdx.z == 1 ? wk
                   : blockIdx.z == 2 ? wv : wo;
    int k0 = blockIdx.x * 64, n0 = blockIdx.y * 64;
    int tx = threadIdx.x & 63, ty = threadIdx.x >> 6;
    for (int i = ty; i < 64; i += 4)
        T[i][tx] = W[(size_t)(k0 + i) * DIMM + n0 + tx];
    __syncthreads();
    f16* dst = wt + (size_t)blockIdx.z * DIMM * DIMM;
    for (int i = ty; i < 64; i += 4)
        dst[(size_t)(n0 + i) * DIMM + k0 + tx] = (f16)T[tx][i];
}

// ---------------------------------------------------------------------------
// Kernel 2: QKV projection GEMM. A fp32 [4096,1024] (cast to f16 in staging),
// B = Wt f16 [n][k]. Output f16 in [b,h,s,d] layout. Scale 1/8 folded into Q.
// grid (32, 8, 3), block 256 (4 waves, 128x128 tile, BK=32)
__global__ __launch_bounds__(256) void k_proj(const float* Aq, const float* Ak,
                                              const float* Av, const f16* wt,
                                              const float* bq, const float* bk,
                                              const float* bv, f16* qkv) {
    __shared__ f16 As[128][40];
    __shared__ f16 Bs[128][40];
    int z = blockIdx.z;
    const float* A    = z == 0 ? Aq : z == 1 ? Ak : Av;
    const float* bias = z == 0 ? bq : z == 1 ? bk : bv;
    const f16* W = wt + (size_t)z * DIMM * DIMM;
    f16* out = qkv + (size_t)z * ZSTRIDE;
    float scale = (z == 0) ? 0.125f : 1.0f;

    int tid = threadIdx.x;
    int lane = tid & 63, wv_ = tid >> 6, quad = lane >> 4, l15 = lane & 15;
    int m0 = (wv_ >> 1) * 64, n0 = (wv_ & 1) * 64;
    int bm = blockIdx.x * 128, bn = blockIdx.y * 128;
    int srow = tid >> 1, shalf = tid & 1;

    f32x4 acc[4][4];
#pragma unroll
    for (int i = 0; i < 4; i++)
#pragma unroll
        for (int j = 0; j < 4; j++) acc[i][j] = {0.f, 0.f, 0.f, 0.f};

    const float* ap0 = A + (size_t)(bm + srow) * DIMM + shalf * 16;
    const f16*   bp0 = W + (size_t)(bn + srow) * DIMM + shalf * 16;

    for (int kk = 0; kk < DIMM; kk += 32) {
        // stage A (fp32 -> f16)
        f16 tmp[16] __attribute__((aligned(16)));
#pragma unroll
        for (int i = 0; i < 16; i += 4) {
            float4 t = *(const float4*)(ap0 + kk + i);
            tmp[i] = (f16)t.x; tmp[i + 1] = (f16)t.y;
            tmp[i + 2] = (f16)t.z; tmp[i + 3] = (f16)t.w;
        }
        *(f16x8*)&As[srow][shalf * 16]     = *(f16x8*)&tmp[0];
        *(f16x8*)&As[srow][shalf * 16 + 8] = *(f16x8*)&tmp[8];
        // stage B (f16)
        f16x8 w0 = *(const f16x8*)(bp0 + kk);
        f16x8 w1 = *(const f16x8*)(bp0 + kk + 8);
        *(f16x8*)&Bs[srow][shalf * 16]     = w0;
        *(f16x8*)&Bs[srow][shalf * 16 + 8] = w1;
        __syncthreads();

        f16x8 af[4], bf[4];
#pragma unroll
        for (int mt = 0; mt < 4; mt++)
            af[mt] = *(const f16x8*)&As[m0 + mt * 16 + l15][quad * 8];
#pragma unroll
        for (int nt = 0; nt < 4; nt++)
            bf[nt] = *(const f16x8*)&Bs[n0 + nt * 16 + l15][quad * 8];
#pragma unroll
        for (int mt = 0; mt < 4; mt++)
#pragma unroll
            for (int nt = 0; nt < 4; nt++)
                acc[mt][nt] = mfma16(af[mt], bf[nt], acc[mt][nt]);
        __syncthreads();
    }

    // epilogue: (acc + bias)*scale -> out[b][h][s][d]
#pragma unroll
    for (int mt = 0; mt < 4; mt++) {
        int gmBase = bm + m0 + mt * 16 + quad * 4;
#pragma unroll
        for (int nt = 0; nt < 4; nt++) {
            int gn = bn + n0 + nt * 16 + l15;
            float bsv = bias[gn];
            int h_ = gn >> 6, d_ = gn & 63;
#pragma unroll
            for (int r = 0; r < 4; r++) {
                int m = gmBase + r;
                int b_ = m >> 11, s_ = m & 2047;
                float val = (acc[mt][nt][r] + bsv) * scale;
                out[(((size_t)b_ * HH + h_) * SS + s_) * DD + d_] = (f16)val;
            }
        }
    }
}

// ---------------------------------------------------------------------------
// Kernel 3: transpose V: vp[bh][s][d] -> vt[bh][d][s]
// grid (32, 32), block 256
__global__ __launch_bounds__(256) void k_vt(const f16* vp, f16* vt) {
    __shared__ f16 T[64][72];
    int s0 = blockIdx.x * 64, bh = blockIdx.y;
    int tx = threadIdx.x & 63, ty = threadIdx.x >> 6;
    const f16* src = vp + ((size_t)bh * SS + s0) * DD;
    for (int i = ty; i < 64; i += 4) T[i][tx] = src[(size_t)i * DD + tx];
    __syncthreads();
    f16* dst = vt + (size_t)bh * DD * SS;
    for (int d = ty; d < 64; d += 4)
        dst[(size_t)d * SS + s0 + tx] = T[tx][d];
}

// ---------------------------------------------------------------------------
// Kernel 4: fused attention. One block per (32 query rows, bh).
// 16 waves; wave w owns 128 logit columns. QK^T in acc regs -> bias+mask ->
// block softmax (fp32) -> write fp32 weights (output 1) + f16 copy to LDS ->
// PV with K split across waves -> LDS reduction -> concat f16 [b][t][h*64+d].
#define WPAD 2056
#define ATTN_SMEM (32 * WPAD * 2 + 32 * 16 * 4 + 32 * 4)
__global__ __launch_bounds__(1024) void k_attn(const f16* qkv, const f16* vt,
                                               const float* bias, const float* pad,
                                               float* outw, f16* concat) {
    extern __shared__ char smem[];
    f16*  w16   = (f16*)smem;
    float* red  = (float*)(smem + 32 * WPAD * 2);
    float* rstat = (float*)(smem + 32 * WPAD * 2 + 32 * 16 * 4);

    int tid = threadIdx.x;
    int w = tid >> 6, lane = tid & 63, quad = lane >> 4, l15 = lane & 15;
    int bh = blockIdx.y;
    int b_ = bh >> 4, h_ = bh & 15;
    int t0 = blockIdx.x * 32;
    int cs = w * 128;

    const f16* qb = qkv + ((size_t)bh * SS + t0) * DD;
    const f16* kb = qkv + ZSTRIDE + (size_t)bh * SS * DD;

    f32x4 acc[2][8];
#pragma unroll
    for (int i = 0; i < 2; i++)
#pragma unroll
        for (int j = 0; j < 8; j++) acc[i][j] = {0.f, 0.f, 0.f, 0.f};

    // ---- QK^T (Q pre-scaled by 1/8) ----
#pragma unroll
    for (int ks = 0; ks < 2; ++ks) {
        f16x8 a0 = *(const f16x8*)(qb + (size_t)l15 * DD + ks * 32 + quad * 8);
        f16x8 a1 = *(const f16x8*)(qb + (size_t)(16 + l15) * DD + ks * 32 + quad * 8);
#pragma unroll
        for (int nt = 0; nt < 8; ++nt) {
            const f16* kp = kb + (size_t)(cs + nt * 16 + l15) * DD + ks * 32 + quad * 8;
            f16x8 bfr = *(const f16x8*)kp;
            acc[0][nt] = mfma16(a0, bfr, acc[0][nt]);
            acc[1][nt] = mfma16(a1, bfr, acc[1][nt]);
        }
    }

    // ---- add bias + padding mask ----
    const float* bptr = bias + ((size_t)bh * SS + t0) * SS;
    const float* padb = pad + (size_t)b_ * SS;
    float prow[2][4];
#pragma unroll
    for (int mt = 0; mt < 2; mt++)
#pragma unroll
        for (int r = 0; r < 4; r++)
            prow[mt][r] = padb[t0 + mt * 16 + quad * 4 + r];
#pragma unroll
    for (int nt = 0; nt < 8; nt++) {
        int s = cs + nt * 16 + l15;
        float pc = padb[s];
#pragma unroll
        for (int mt = 0; mt < 2; mt++) {
#pragma unroll
            for (int r = 0; r < 4; r++) {
                int rl = mt * 16 + quad * 4 + r;
                float msk = -1e9f * (1.0f - (1.0f - prow[mt][r]) * (1.0f - pc));
                acc[mt][nt][r] += bptr[(size_t)rl * SS + s] + msk;
            }
        }
    }

    // ---- row max (in-lane -> quad shuffle -> cross-wave via LDS) ----
    float pm[2][4];
#pragma unroll
    for (int mt = 0; mt < 2; mt++)
#pragma unroll
        for (int r = 0; r < 4; r++) {
            float m = -3e38f;
#pragma unroll
            for (int nt = 0; nt < 8; nt++) m = fmaxf(m, acc[mt][nt][r]);
            pm[mt][r] = m;
        }
    for (int off = 1; off < 16; off <<= 1) {
#pragma unroll
        for (int mt = 0; mt < 2; mt++)
#pragma unroll
            for (int r = 0; r < 4; r++)
                pm[mt][r] = fmaxf(pm[mt][r], __shfl_xor(pm[mt][r], off));
    }
    if (l15 == 0) {
#pragma unroll
        for (int mt = 0; mt < 2; mt++)
#pragma unroll
            for (int r = 0; r < 4; r++)
                red[(mt * 16 + quad * 4 + r) * 16 + w] = pm[mt][r];
    }
    __syncthreads();
    if (tid < 32) {
        float m = -3e38f;
        for (int i = 0; i < 16; i++) m = fmaxf(m, red[tid * 16 + i]);
        rstat[tid] = m;
    }
    __syncthreads();

    // ---- exp + row sum ----
    float psum[2][4];
#pragma unroll
    for (int mt = 0; mt < 2; mt++)
#pragma unroll
        for (int r = 0; r < 4; r++) {
            float rm = rstat[mt * 16 + quad * 4 + r];
            float s = 0.f;
#pragma unroll
            for (int nt = 0; nt < 8; nt++) {
                float e = __expf(acc[mt][nt][r] - rm);
                acc[mt][nt][r] = e;
                s += e;
            }
            psum[mt][r] = s;
        }
    for (int off = 1; off < 16; off <<= 1) {
#pragma unroll
        for (int mt = 0; mt < 2; mt++)
#pragma unroll
            for (int r = 0; r < 4; r++)
                psum[mt][r] += __shfl_xor(psum[mt][r], off);
    }
    if (l15 == 0) {
#pragma unroll
        for (int mt = 0; mt < 2; mt++)
#pragma unroll
            for (int r = 0; r < 4; r++)
                red[(mt * 16 + quad * 4 + r) * 16 + w] = psum[mt][r];
    }
    __syncthreads();
    if (tid < 32) {
        float s = 0.f;
        for (int i = 0; i < 16; i++) s += red[tid * 16 + i];
        rstat[tid] = 1.0f / s;
    }
    __syncthreads();

    // ---- normalize: write fp32 weights (output 1) + f16 copy into LDS ----
    float* wout = outw + ((size_t)bh * SS + t0) * SS;
#pragma unroll
    for (int mt = 0; mt < 2; mt++) {
#pragma unroll
        for (int r = 0; r < 4; r++) {
            int rl = mt * 16 + quad * 4 + r;
            float rinv = rstat[rl];
#pragma unroll
            for (int nt = 0; nt < 8; nt++) {
                int s = cs + nt * 16 + l15;
                float v = acc[mt][nt][r] * rinv;
                wout[(size_t)rl * SS + s] = v;
                w16[rl * WPAD + s] = (f16)v;
            }
        }
    }
    __syncthreads();

    // ---- PV: wave w handles K-chunk [w*128, w*128+128) ----
    f32x4 pacc[2][4];
#pragma unroll
    for (int i = 0; i < 2; i++)
#pragma unroll
        for (int j = 0; j < 4; j++) pacc[i][j] = {0.f, 0.f, 0.f, 0.f};
    const f16* vtb = vt + (size_t)bh * DD * SS;
#pragma unroll
    for (int ks = 0; ks < 4; ++ks) {
        int k0 = w * 128 + ks * 32;
        f16x8 a0 = *(const f16x8*)&w16[(0 + l15) * WPAD + k0 + quad * 8];
        f16x8 a1 = *(const f16x8*)&w16[(16 + l15) * WPAD + k0 + quad * 8];
#pragma unroll
        for (int nd = 0; nd < 4; ++nd) {
            f16x8 bv = *(const f16x8*)(vtb + (size_t)(nd * 16 + l15) * SS + k0 + quad * 8);
            pacc[0][nd] = mfma16(a0, bv, pacc[0][nd]);
            pacc[1][nd] = mfma16(a1, bv, pacc[1][nd]);
        }
    }
    __syncthreads();   // all w16 reads done; reuse region for partials

    float* part = (float*)smem;   // [16 waves][32 rows][64 cols]
#pragma unroll
    for (int mt = 0; mt < 2; mt++)
#pragma unroll
        for (int nd = 0; nd < 4; nd++)
#pragma unroll
            for (int r = 0; r < 4; r++)
                part[((w * 32) + mt * 16 + quad * 4 + r) * 64 + nd * 16 + l15] =
                    pacc[mt][nd][r];
    __syncthreads();

#pragma unroll
    for (int e = tid; e < 2048; e += 1024) {
        int row = e >> 6, col = e & 63;
        float ssum = 0.f;
#pragma unroll
        for (int w2 = 0; w2 < 16; ++w2) ssum += part[(w2 * 32 + row) * 64 + col];
        concat[((size_t)b_ * SS + t0 + row) * DIMM + h_ * DD + col] = (f16)ssum;
    }
}

// ---------------------------------------------------------------------------
// Kernel 5: output projection. A = concat f16 [4096,1024], B = wo_t f16.
// fp32 output to d_out[0 : 4194304]. grid (32,8), block 256.
__global__ __launch_bounds__(256) void k_outproj(const f16* A, const f16* W,
                                                 const float* bias, float* out) {
    __shared__ f16 As[128][40];
    __shared__ f16 Bs[128][40];
    int tid = threadIdx.x;
    int lane = tid & 63, wv_ = tid >> 6, quad = lane >> 4, l15 = lane & 15;
    int m0 = (wv_ >> 1) * 64, n0 = (wv_ & 1) * 64;
    int bm = blockIdx.x * 128, bn = blockIdx.y * 128;
    int srow = tid >> 1, shalf = tid & 1;

    f32x4 acc[4][4];
#pragma unroll
    for (int i = 0; i < 4; i++)
#pragma unroll
        for (int j = 0; j < 4; j++) acc[i][j] = {0.f, 0.f, 0.f, 0.f};

    const f16* ap0 = A + (size_t)(bm + srow) * DIMM + shalf * 16;
    const f16* bp0 = W + (size_t)(bn + srow) * DIMM + shalf * 16;

    for (int kk = 0; kk < DIMM; kk += 32) {
        f16x8 x0 = *(const f16x8*)(ap0 + kk);
        f16x8 x1 = *(const f16x8*)(ap0 + kk + 8);
        *(f16x8*)&As[srow][shalf * 16]     = x0;
        *(f16x8*)&As[srow][shalf * 16 + 8] = x1;
        f16x8 w0 = *(const f16x8*)(bp0 + kk);
        f16x8 w1 = *(const f16x8*)(bp0 + kk + 8);
        *(f16x8*)&Bs[srow][shalf * 16]     = w0;
        *(f16x8*)&Bs[srow][shalf * 16 + 8] = w1;
        __syncthreads();

        f16x8 af[4], bf[4];
#pragma unroll
        for (int mt = 0; mt < 4; mt++)
            af[mt] = *(const f16x8*)&As[m0 + mt * 16 + l15][quad * 8];
#pragma unroll
        for (int nt = 0; nt < 4; nt++)
            bf[nt] = *(const f16x8*)&Bs[n0 + nt * 16 + l15][quad * 8];
#pragma unroll
        for (int mt = 0; mt < 4; mt++)
#pragma unroll
            for (int nt = 0; nt < 4; nt++)
                acc[mt][nt] = mfma16(af[mt], bf[nt], acc[mt][nt]);
        __syncthreads();
    }

#pragma unroll
    for (int mt = 0; mt < 4; mt++) {
        int gmBase = bm + m0 + mt * 16 + quad * 4;
#pragma unroll
        for (int nt = 0; nt < 4; nt++) {
            int gn = bn + n0 + nt * 16 + l15;
            float bsv = bias[gn];
#pragma unroll
            for (int r = 0; r < 4; r++)
                out[(size_t)(gmBase + r) * DIMM + gn] = acc[mt][nt][r] + bsv;
        }
    }
}

// ---------------------------------------------------------------------------
extern "C" void kernel_launch(void* const* d_in, const int* in_sizes, int n_in,
                              void* d_out, int out_size, void* d_ws, size_t ws_size,
                              hipStream_t stream) {
    const float* query = (const float*)d_in[0];
    const float* key   = (const float*)d_in[1];
    const float* value = (const float*)d_in[2];
    const float* abias = (const float*)d_in[3];
    const float* padd  = (const float*)d_in[4];
    const float* wq_w = (const float*)d_in[5];
    const float* wq_b = (const float*)d_in[6];
    const float* wk_w = (const float*)d_in[7];
    const float* wk_b = (const float*)d_in[8];
    const float* wv_w = (const float*)d_in[9];
    const float* wv_b = (const float*)d_in[10];
    const float* wo_w = (const float*)d_in[11];
    const float* wo_b = (const float*)d_in[12];

    float* out  = (float*)d_out;
    float* outw = out + (size_t)MMN * DIMM;   // attention_weights region

    char* ws = (char*)d_ws;
    f16* wt   = (f16*)ws;                                     // 4 * 1M f16
    f16* qkv  = (f16*)(ws + (size_t)4 * DIMM * DIMM * 2);     // 3 * 4.2M f16
    f16* vt   = (f16*)(ws + (size_t)4 * DIMM * DIMM * 2 + (size_t)3 * ZSTRIDE * 2);
    f16* ccat = vt + (size_t)BHN * DD * SS;                   // 4.2M f16

    // allow >64KB dynamic LDS for k_attn (idempotent; not a stream op)
    hipFuncSetAttribute(reinterpret_cast<const void*>(k_attn),
                        hipFuncAttributeMaxDynamicSharedMemorySize, ATTN_SMEM);

    k_wt<<<dim3(16, 16, 4), 256, 0, stream>>>(wq_w, wk_w, wv_w, wo_w, wt);
    k_proj<<<dim3(32, 8, 3), 256, 0, stream>>>(query, key, value, wt,
                                               wq_b, wk_b, wv_b, qkv);
    k_vt<<<dim3(32, 32), 256, 0, stream>>>(qkv + (size_t)2 * ZSTRIDE, vt);
    k_attn<<<dim3(64, 32), 1024, ATTN_SMEM, stream>>>(qkv, vt, abias, padd,
                                                      outw, ccat);
    k_outproj<<<dim3(32, 8), 256, 0, stream>>>(ccat, wt + (size_t)3 * DIMM * DIMM,
                                               wo_b, out);
}